// Round 1
// baseline (68311.713 us; speedup 1.0000x reference)
//
#include <hip/hip_runtime.h>
#include <math.h>

#define H 51
#define NG 204            // 4*H
#define LSEQ 999
#define BTOT 2048
#define MATD (H * NG)     // 10404 dwords per reordered matrix

// ws layout (dword offsets)
#define OFF_WHH1 0
#define OFF_WIH2 (1 * MATD)
#define OFF_WHH2 (2 * MATD)
#define OFF_WIH1 (3 * MATD)          // 204
#define OFF_B1   (OFF_WIH1 + NG)     // 204
#define OFF_B2   (OFF_B1 + NG)       // 204
#define OFF_WLIN (OFF_B2 + NG)       // 51
#define OFF_BLIN (OFF_WLIN + H)      // 1
#define WS_DWORDS (OFF_BLIN + 1)

#define LDS_DWORDS (3 * MATD + 64)   // +64 pad so lanes 51..63 b128 reads stay in-bounds

// ---------------- prep: reorder weights into k-major, gate-interleaved ----------------
// W''[mat][k][j*4+m] = W[m*51+j][k]   (m: 0=i,1=f,2=g,3=o ; j = hidden unit)
__global__ void prep_kernel(const float* __restrict__ Wih1, const float* __restrict__ Whh1,
                            const float* __restrict__ bih1, const float* __restrict__ bhh1,
                            const float* __restrict__ Wih2, const float* __restrict__ Whh2,
                            const float* __restrict__ bih2, const float* __restrict__ bhh2,
                            const float* __restrict__ Wlin, const float* __restrict__ blin,
                            float* __restrict__ ws) {
    int tid = threadIdx.x + blockIdx.x * blockDim.x;
    int nthr = blockDim.x * gridDim.x;
    for (int idx = tid; idx < 3 * H * NG; idx += nthr) {
        int mat = idx / (H * NG);
        int rem = idx % (H * NG);
        int k = rem / NG;
        int c = rem % NG;            // c = j*4 + m
        int j = c >> 2, m = c & 3;
        const float* W = (mat == 0) ? Whh1 : (mat == 1) ? Wih2 : Whh2;
        ws[mat * MATD + k * NG + c] = W[(m * H + j) * H + k];
    }
    for (int c = tid; c < NG; c += nthr) {
        int j = c >> 2, m = c & 3;
        ws[OFF_WIH1 + c] = Wih1[m * H + j];                     // W_ih1 is [204][1]
        ws[OFF_B1 + c]   = bih1[m * H + j] + bhh1[m * H + j];
        ws[OFF_B2 + c]   = bih2[m * H + j] + bhh2[m * H + j];
    }
    for (int j = tid; j < H; j += nthr) ws[OFF_WLIN + j] = Wlin[j];
    if (tid == 0) ws[OFF_BLIN] = blin[0];
}

// ---------------- main LSTM kernel ----------------
__device__ __forceinline__ float bcast(float v, int k) {
    return __int_as_float(__builtin_amdgcn_readlane(__float_as_int(v), k));
}
__device__ __forceinline__ float sigm(float x) {
    return __builtin_amdgcn_rcpf(1.0f + __expf(-x));
}
__device__ __forceinline__ float tanh_(float x) {
    // 1 - 2/(exp(2x)+1); stable at both ends
    return fmaf(-2.0f, __builtin_amdgcn_rcpf(__expf(2.0f * x) + 1.0f), 1.0f);
}

extern __shared__ float lds[];

__global__ void __launch_bounds__(256)
lstm_kernel(const float* __restrict__ x, const float* __restrict__ ws,
            float* __restrict__ out) {
    const int tid = threadIdx.x;
    const int wave = tid >> 6;
    const int lane = tid & 63;
    const int j = lane;

    // stage reordered weights into LDS (3 matrices)
    for (int i = tid; i < 3 * MATD; i += 256) lds[i] = ws[i];
    for (int i = 3 * MATD + tid; i < LDS_DWORDS; i += 256) lds[i] = 0.0f;
    __syncthreads();

    const float* whh1 = lds + OFF_WHH1 + j * 4;
    const float* wih2 = lds + OFF_WIH2 + j * 4;
    const float* whh2 = lds + OFF_WHH2 + j * 4;

    const bool act = (j < H);
    float wih1r[4], b1r[4], b2r[4];
#pragma unroll
    for (int m = 0; m < 4; m++) {
        int c = j * 4 + m;
        wih1r[m] = act ? ws[OFF_WIH1 + c] : 0.0f;
        b1r[m]   = act ? ws[OFF_B1 + c]   : 0.0f;
        b2r[m]   = act ? ws[OFF_B2 + c]   : 0.0f;
    }
    const float wlinr = act ? ws[OFF_WLIN + j] : 0.0f;
    const float blinv = ws[OFF_BLIN];

    const int b0 = blockIdx.x * 8 + wave * 2;
    const float* x0p = x + (size_t)b0 * LSEQ;
    const float* x1p = x + (size_t)(b0 + 1) * LSEQ;
    float* o0p = out + (size_t)b0 * LSEQ;
    float* o1p = out + (size_t)(b0 + 1) * LSEQ;

    // per-lane state: unit j of each of the two batch elements
    float h1a = 0.f, c1a = 0.f, h2a = 0.f, c2a = 0.f;
    float h1b = 0.f, c1b = 0.f, h2b = 0.f, c2b = 0.f;

    for (int t = 0; t < LSEQ; t++) {
        float xa = x0p[t];
        float xb = x1p[t];

        // ---- layer 1 gates ----
        float A0[4], A1[4];
#pragma unroll
        for (int m = 0; m < 4; m++) {
            A0[m] = fmaf(xa, wih1r[m], b1r[m]);
            A1[m] = fmaf(xb, wih1r[m], b1r[m]);
        }
#pragma unroll
        for (int k = 0; k < H; k++) {
            float4 w = *(const float4*)(whh1 + k * NG);
            float sa = bcast(h1a, k);
            float sb = bcast(h1b, k);
            A0[0] = fmaf(w.x, sa, A0[0]); A0[1] = fmaf(w.y, sa, A0[1]);
            A0[2] = fmaf(w.z, sa, A0[2]); A0[3] = fmaf(w.w, sa, A0[3]);
            A1[0] = fmaf(w.x, sb, A1[0]); A1[1] = fmaf(w.y, sb, A1[1]);
            A1[2] = fmaf(w.z, sb, A1[2]); A1[3] = fmaf(w.w, sb, A1[3]);
        }
        // activations (i=A[0], f=A[1], g=A[2], o=A[3])
        c1a = sigm(A0[1]) * c1a + sigm(A0[0]) * tanh_(A0[2]);
        h1a = sigm(A0[3]) * tanh_(c1a);
        c1b = sigm(A1[1]) * c1b + sigm(A1[0]) * tanh_(A1[2]);
        h1b = sigm(A1[3]) * tanh_(c1b);

        // ---- layer 2 gates (two matvecs fused) ----
#pragma unroll
        for (int m = 0; m < 4; m++) { A0[m] = b2r[m]; A1[m] = b2r[m]; }
#pragma unroll
        for (int k = 0; k < H; k++) {
            float4 u = *(const float4*)(wih2 + k * NG);
            float4 v = *(const float4*)(whh2 + k * NG);
            float sa = bcast(h1a, k);
            float sb = bcast(h1b, k);
            float ta = bcast(h2a, k);
            float tb = bcast(h2b, k);
            A0[0] = fmaf(u.x, sa, A0[0]); A0[1] = fmaf(u.y, sa, A0[1]);
            A0[2] = fmaf(u.z, sa, A0[2]); A0[3] = fmaf(u.w, sa, A0[3]);
            A0[0] = fmaf(v.x, ta, A0[0]); A0[1] = fmaf(v.y, ta, A0[1]);
            A0[2] = fmaf(v.z, ta, A0[2]); A0[3] = fmaf(v.w, ta, A0[3]);
            A1[0] = fmaf(u.x, sb, A1[0]); A1[1] = fmaf(u.y, sb, A1[1]);
            A1[2] = fmaf(u.z, sb, A1[2]); A1[3] = fmaf(u.w, sb, A1[3]);
            A1[0] = fmaf(v.x, tb, A1[0]); A1[1] = fmaf(v.y, tb, A1[1]);
            A1[2] = fmaf(v.z, tb, A1[2]); A1[3] = fmaf(v.w, tb, A1[3]);
        }
        c2a = sigm(A0[1]) * c2a + sigm(A0[0]) * tanh_(A0[2]);
        h2a = sigm(A0[3]) * tanh_(c2a);
        c2b = sigm(A1[1]) * c2b + sigm(A1[0]) * tanh_(A1[2]);
        h2b = sigm(A1[3]) * tanh_(c2b);

        // ---- output: dot(W_lin, h2_new) + b_lin ----
        float ra = wlinr * h2a;   // lanes >= 51 contribute 0 (wlinr == 0)
        float rb = wlinr * h2b;
#pragma unroll
        for (int off = 32; off >= 1; off >>= 1) {
            ra += __shfl_down(ra, off);
            rb += __shfl_down(rb, off);
        }
        if (lane == 0) {
            o0p[t] = ra + blinv;
            o1p[t] = rb + blinv;
        }
    }
}

extern "C" void kernel_launch(void* const* d_in, const int* in_sizes, int n_in,
                              void* d_out, int out_size, void* d_ws, size_t ws_size,
                              hipStream_t stream) {
    const float* x    = (const float*)d_in[0];
    const float* Wih1 = (const float*)d_in[1];
    const float* Whh1 = (const float*)d_in[2];
    const float* bih1 = (const float*)d_in[3];
    const float* bhh1 = (const float*)d_in[4];
    const float* Wih2 = (const float*)d_in[5];
    const float* Whh2 = (const float*)d_in[6];
    const float* bih2 = (const float*)d_in[7];
    const float* bhh2 = (const float*)d_in[8];
    const float* Wlin = (const float*)d_in[9];
    const float* blin = (const float*)d_in[10];
    float* ws  = (float*)d_ws;
    float* out = (float*)d_out;

    hipLaunchKernelGGL(prep_kernel, dim3(4), dim3(256), 0, stream,
                       Wih1, Whh1, bih1, bhh1, Wih2, Whh2, bih2, bhh2, Wlin, blin, ws);

    size_t lds_bytes = (size_t)LDS_DWORDS * 4;
    (void)hipFuncSetAttribute((const void*)lstm_kernel,
                              hipFuncAttributeMaxDynamicSharedMemorySize, (int)lds_bytes);
    hipLaunchKernelGGL(lstm_kernel, dim3(BTOT / 8), dim3(256), lds_bytes, stream,
                       x, ws, out);
}

// Round 2
// 60939.465 us; speedup vs baseline: 1.1210x; 1.1210x over previous
//
#include <hip/hip_runtime.h>
#include <math.h>

#define H 51
#define NG 204            // 4*H
#define LSEQ 999
#define BTOT 2048
#define MATD (H * NG)     // 10404 dwords per reordered matrix

// ws layout (dword offsets)
#define OFF_WHH1 0
#define OFF_WIH2 (1 * MATD)
#define OFF_WHH2 (2 * MATD)
#define OFF_WIH1 (3 * MATD)          // 204
#define OFF_B1   (OFF_WIH1 + NG)     // 204
#define OFF_B2   (OFF_B1 + NG)       // 204
#define OFF_WLIN (OFF_B2 + NG)       // 51
#define OFF_BLIN (OFF_WLIN + H)      // 1
#define WS_DWORDS (OFF_BLIN + 1)

#define LDS_DWORDS (3 * MATD + 64)   // +64 pad so lanes 51..63 b128 reads stay in-bounds

// ---------------- prep: reorder weights into k-major, gate-interleaved ----------------
// W''[mat][k][j*4+m] = W[m*51+j][k]   (m: 0=i,1=f,2=g,3=o ; j = hidden unit)
__global__ void prep_kernel(const float* __restrict__ Wih1, const float* __restrict__ Whh1,
                            const float* __restrict__ bih1, const float* __restrict__ bhh1,
                            const float* __restrict__ Wih2, const float* __restrict__ Whh2,
                            const float* __restrict__ bih2, const float* __restrict__ bhh2,
                            const float* __restrict__ Wlin, const float* __restrict__ blin,
                            float* __restrict__ ws) {
    int tid = threadIdx.x + blockIdx.x * blockDim.x;
    int nthr = blockDim.x * gridDim.x;
    for (int idx = tid; idx < 3 * H * NG; idx += nthr) {
        int mat = idx / (H * NG);
        int rem = idx % (H * NG);
        int k = rem / NG;
        int c = rem % NG;            // c = j*4 + m
        int j = c >> 2, m = c & 3;
        const float* W = (mat == 0) ? Whh1 : (mat == 1) ? Wih2 : Whh2;
        ws[mat * MATD + k * NG + c] = W[(m * H + j) * H + k];
    }
    for (int c = tid; c < NG; c += nthr) {
        int j = c >> 2, m = c & 3;
        ws[OFF_WIH1 + c] = Wih1[m * H + j];                     // W_ih1 is [204][1]
        ws[OFF_B1 + c]   = bih1[m * H + j] + bhh1[m * H + j];
        ws[OFF_B2 + c]   = bih2[m * H + j] + bhh2[m * H + j];
    }
    for (int j = tid; j < H; j += nthr) ws[OFF_WLIN + j] = Wlin[j];
    if (tid == 0) ws[OFF_BLIN] = blin[0];
}

// ---------------- main LSTM kernel ----------------
__device__ __forceinline__ float bcast(float v, int k) {
    return __int_as_float(__builtin_amdgcn_readlane(__float_as_int(v), k));
}
__device__ __forceinline__ float sigm(float x) {
    return __builtin_amdgcn_rcpf(1.0f + __expf(-x));
}
__device__ __forceinline__ float tanh_(float x) {
    // 1 - 2/(exp(2x)+1); stable at both ends
    return fmaf(-2.0f, __builtin_amdgcn_rcpf(__expf(2.0f * x) + 1.0f), 1.0f);
}

extern __shared__ float lds[];

__global__ void __launch_bounds__(256, 1)
lstm_kernel(const float* __restrict__ x, const float* __restrict__ ws,
            float* __restrict__ out) {
    const int tid = threadIdx.x;
    const int wave = tid >> 6;
    const int lane = tid & 63;
    const int j = lane;

    // stage reordered weights into LDS (3 matrices)
    for (int i = tid; i < 3 * MATD; i += 256) lds[i] = ws[i];
    for (int i = 3 * MATD + tid; i < LDS_DWORDS; i += 256) lds[i] = 0.0f;
    __syncthreads();

    const float* whh1 = lds + OFF_WHH1 + j * 4;
    const float* wih2 = lds + OFF_WIH2 + j * 4;
    const float* whh2 = lds + OFF_WHH2 + j * 4;

    const bool act = (j < H);
    float wih1r[4], b1r[4], b2r[4];
#pragma unroll
    for (int m = 0; m < 4; m++) {
        int c = j * 4 + m;
        wih1r[m] = act ? ws[OFF_WIH1 + c] : 0.0f;
        b1r[m]   = act ? ws[OFF_B1 + c]   : 0.0f;
        b2r[m]   = act ? ws[OFF_B2 + c]   : 0.0f;
    }
    const float wlinr = act ? ws[OFF_WLIN + j] : 0.0f;
    const float blinv = ws[OFF_BLIN];

    const int b0 = blockIdx.x * 8 + wave * 2;
    const float* x0p = x + (size_t)b0 * LSEQ;
    const float* x1p = x + (size_t)(b0 + 1) * LSEQ;
    float* o0p = out + (size_t)b0 * LSEQ;
    float* o1p = out + (size_t)(b0 + 1) * LSEQ;

    // per-lane state: unit j of each of the two batch elements
    float h1a = 0.f, c1a = 0.f, h2a = 0.f, c2a = 0.f;
    float h1b = 0.f, c1b = 0.f, h2b = 0.f, c2b = 0.f;

    // x prefetch (uniform scalar loads; issue one iteration ahead)
    float xa = x0p[0];
    float xb = x1p[0];

    for (int t = 0; t < LSEQ; t++) {
        // issue next-step x loads early; consumed next iteration
        const int tn = (t + 1 < LSEQ) ? (t + 1) : t;
        float xa_n = x0p[tn];
        float xb_n = x1p[tn];

        // ---- layer 1 gates ----
        float A0[4], A1[4];
#pragma unroll
        for (int m = 0; m < 4; m++) {
            A0[m] = fmaf(xa, wih1r[m], b1r[m]);
            A1[m] = fmaf(xb, wih1r[m], b1r[m]);
        }
#pragma unroll 8
        for (int k = 0; k < H; k++) {
            float4 w = *(const float4*)(whh1 + k * NG);
            float sa = bcast(h1a, k);
            float sb = bcast(h1b, k);
            A0[0] = fmaf(w.x, sa, A0[0]); A0[1] = fmaf(w.y, sa, A0[1]);
            A0[2] = fmaf(w.z, sa, A0[2]); A0[3] = fmaf(w.w, sa, A0[3]);
            A1[0] = fmaf(w.x, sb, A1[0]); A1[1] = fmaf(w.y, sb, A1[1]);
            A1[2] = fmaf(w.z, sb, A1[2]); A1[3] = fmaf(w.w, sb, A1[3]);
        }
        // activations (i=A[0], f=A[1], g=A[2], o=A[3])
        c1a = sigm(A0[1]) * c1a + sigm(A0[0]) * tanh_(A0[2]);
        h1a = sigm(A0[3]) * tanh_(c1a);
        c1b = sigm(A1[1]) * c1b + sigm(A1[0]) * tanh_(A1[2]);
        h1b = sigm(A1[3]) * tanh_(c1b);

        // ---- layer 2 gates (two matvecs fused) ----
#pragma unroll
        for (int m = 0; m < 4; m++) { A0[m] = b2r[m]; A1[m] = b2r[m]; }
#pragma unroll 4
        for (int k = 0; k < H; k++) {
            float4 u = *(const float4*)(wih2 + k * NG);
            float4 v = *(const float4*)(whh2 + k * NG);
            float sa = bcast(h1a, k);
            float sb = bcast(h1b, k);
            float ta = bcast(h2a, k);
            float tb = bcast(h2b, k);
            A0[0] = fmaf(u.x, sa, A0[0]); A0[1] = fmaf(u.y, sa, A0[1]);
            A0[2] = fmaf(u.z, sa, A0[2]); A0[3] = fmaf(u.w, sa, A0[3]);
            A0[0] = fmaf(v.x, ta, A0[0]); A0[1] = fmaf(v.y, ta, A0[1]);
            A0[2] = fmaf(v.z, ta, A0[2]); A0[3] = fmaf(v.w, ta, A0[3]);
            A1[0] = fmaf(u.x, sb, A1[0]); A1[1] = fmaf(u.y, sb, A1[1]);
            A1[2] = fmaf(u.z, sb, A1[2]); A1[3] = fmaf(u.w, sb, A1[3]);
            A1[0] = fmaf(v.x, tb, A1[0]); A1[1] = fmaf(v.y, tb, A1[1]);
            A1[2] = fmaf(v.z, tb, A1[2]); A1[3] = fmaf(v.w, tb, A1[3]);
        }
        c2a = sigm(A0[1]) * c2a + sigm(A0[0]) * tanh_(A0[2]);
        h2a = sigm(A0[3]) * tanh_(c2a);
        c2b = sigm(A1[1]) * c2b + sigm(A1[0]) * tanh_(A1[2]);
        h2b = sigm(A1[3]) * tanh_(c2b);

        // ---- output: dot(W_lin, h2_new) + b_lin ----
        float ra = wlinr * h2a;   // lanes >= 51 contribute 0 (wlinr == 0)
        float rb = wlinr * h2b;
#pragma unroll
        for (int off = 32; off >= 1; off >>= 1) {
            ra += __shfl_down(ra, off);
            rb += __shfl_down(rb, off);
        }
        if (lane == 0) {
            o0p[t] = ra + blinv;
            o1p[t] = rb + blinv;
        }

        xa = xa_n;
        xb = xb_n;
    }
}

extern "C" void kernel_launch(void* const* d_in, const int* in_sizes, int n_in,
                              void* d_out, int out_size, void* d_ws, size_t ws_size,
                              hipStream_t stream) {
    const float* x    = (const float*)d_in[0];
    const float* Wih1 = (const float*)d_in[1];
    const float* Whh1 = (const float*)d_in[2];
    const float* bih1 = (const float*)d_in[3];
    const float* bhh1 = (const float*)d_in[4];
    const float* Wih2 = (const float*)d_in[5];
    const float* Whh2 = (const float*)d_in[6];
    const float* bih2 = (const float*)d_in[7];
    const float* bhh2 = (const float*)d_in[8];
    const float* Wlin = (const float*)d_in[9];
    const float* blin = (const float*)d_in[10];
    float* ws  = (float*)d_ws;
    float* out = (float*)d_out;

    hipLaunchKernelGGL(prep_kernel, dim3(4), dim3(256), 0, stream,
                       Wih1, Whh1, bih1, bhh1, Wih2, Whh2, bih2, bhh2, Wlin, blin, ws);

    size_t lds_bytes = (size_t)LDS_DWORDS * 4;
    (void)hipFuncSetAttribute((const void*)lstm_kernel,
                              hipFuncAttributeMaxDynamicSharedMemorySize, (int)lds_bytes);
    hipLaunchKernelGGL(lstm_kernel, dim3(BTOT / 8), dim3(256), lds_bytes, stream,
                       x, ws, out);
}

// Round 3
// 11425.863 us; speedup vs baseline: 5.9787x; 5.3335x over previous
//
#include <hip/hip_runtime.h>
#include <math.h>

#define H 51
#define NG 204            // 4*H
#define LSEQ 999
#define BTOT 2048
#define MATD (H * NG)     // 10404 dwords per reordered matrix

// ws layout (dword offsets)
#define OFF_WHH1 0
#define OFF_WIH2 (1 * MATD)
#define OFF_WHH2 (2 * MATD)
#define OFF_WIH1 (3 * MATD)          // 204
#define OFF_B1   (OFF_WIH1 + NG)     // 204
#define OFF_B2   (OFF_B1 + NG)       // 204
#define OFF_WLIN (OFF_B2 + NG)       // 51
#define OFF_BLIN (OFF_WLIN + H)      // 1
#define WS_DWORDS (OFF_BLIN + 1)

#define LDS_DWORDS (3 * MATD + 64)   // +64 pad so lanes 51..63 b128 reads stay in-bounds

// ---------------- prep: reorder weights into k-major, gate-interleaved ----------------
// W''[mat][k][j*4+m] = W[m*51+j][k]   (m: 0=i,1=f,2=g,3=o ; j = hidden unit)
__global__ void prep_kernel(const float* __restrict__ Wih1, const float* __restrict__ Whh1,
                            const float* __restrict__ bih1, const float* __restrict__ bhh1,
                            const float* __restrict__ Wih2, const float* __restrict__ Whh2,
                            const float* __restrict__ bih2, const float* __restrict__ bhh2,
                            const float* __restrict__ Wlin, const float* __restrict__ blin,
                            float* __restrict__ ws) {
    int tid = threadIdx.x + blockIdx.x * blockDim.x;
    int nthr = blockDim.x * gridDim.x;
    for (int idx = tid; idx < 3 * H * NG; idx += nthr) {
        int mat = idx / (H * NG);
        int rem = idx % (H * NG);
        int k = rem / NG;
        int c = rem % NG;            // c = j*4 + m
        int j = c >> 2, m = c & 3;
        const float* W = (mat == 0) ? Whh1 : (mat == 1) ? Wih2 : Whh2;
        ws[mat * MATD + k * NG + c] = W[(m * H + j) * H + k];
    }
    for (int c = tid; c < NG; c += nthr) {
        int j = c >> 2, m = c & 3;
        ws[OFF_WIH1 + c] = Wih1[m * H + j];                     // W_ih1 is [204][1]
        ws[OFF_B1 + c]   = bih1[m * H + j] + bhh1[m * H + j];
        ws[OFF_B2 + c]   = bih2[m * H + j] + bhh2[m * H + j];
    }
    for (int j = tid; j < H; j += nthr) ws[OFF_WLIN + j] = Wlin[j];
    if (tid == 0) ws[OFF_BLIN] = blin[0];
}

// ---------------- main LSTM kernel ----------------
__device__ __forceinline__ float bcast(float v, int k) {
    return __int_as_float(__builtin_amdgcn_readlane(__float_as_int(v), k));
}
__device__ __forceinline__ float sigm(float x) {
    return __builtin_amdgcn_rcpf(1.0f + __expf(-x));
}
__device__ __forceinline__ float tanh_(float x) {
    // 1 - 2/(exp(2x)+1); stable at both ends
    return fmaf(-2.0f, __builtin_amdgcn_rcpf(__expf(2.0f * x) + 1.0f), 1.0f);
}

extern __shared__ float lds[];

__global__ void __launch_bounds__(256, 1)
lstm_kernel(const float* __restrict__ x, const float* __restrict__ ws,
            float* __restrict__ out) {
    const int tid = threadIdx.x;
    const int wave = tid >> 6;
    const int lane = tid & 63;
    const int j = lane;

    // stage reordered weights into LDS (3 matrices)
    for (int i = tid; i < 3 * MATD; i += 256) lds[i] = ws[i];
    for (int i = 3 * MATD + tid; i < LDS_DWORDS; i += 256) lds[i] = 0.0f;
    __syncthreads();

    const float* whh1 = lds + OFF_WHH1 + j * 4;
    const float* wih2 = lds + OFF_WIH2 + j * 4;
    const float* whh2 = lds + OFF_WHH2 + j * 4;

    const bool act = (j < H);
    float wih1r[4], b1r[4], b2r[4];
#pragma unroll
    for (int m = 0; m < 4; m++) {
        int c = j * 4 + m;
        wih1r[m] = act ? ws[OFF_WIH1 + c] : 0.0f;
        b1r[m]   = act ? ws[OFF_B1 + c]   : 0.0f;
        b2r[m]   = act ? ws[OFF_B2 + c]   : 0.0f;
    }
    const float wlinr = act ? ws[OFF_WLIN + j] : 0.0f;
    const float blinv = ws[OFF_BLIN];

    const int b0 = blockIdx.x * 8 + wave * 2;
    const float* x0p = x + (size_t)b0 * LSEQ;
    const float* x1p = x + (size_t)(b0 + 1) * LSEQ;
    float* o0p = out + (size_t)b0 * LSEQ;
    float* o1p = out + (size_t)(b0 + 1) * LSEQ;

    // per-lane state: unit j of each of the two batch elements
    float h1a = 0.f, c1a = 0.f, h2a = 0.f, c2a = 0.f;
    float h1b = 0.f, c1b = 0.f, h2b = 0.f, c2b = 0.f;

    // x prefetch (uniform scalar loads; issue one iteration ahead)
    float xa = x0p[0];
    float xb = x1p[0];

    for (int t = 0; t < LSEQ; t++) {
        // Fence: a may-write-memory op inside the loop stops LICM from
        // hoisting the (t-invariant) LDS weight loads out of the 999-step
        // loop — that hoist demands ~612 VGPRs and spilled everything to
        // scratch (rounds 1-2: 129 GB FETCH, VGPR=256 cap, 9% VALUBusy).
        asm volatile("" ::: "memory");

        // issue next-step x loads early; consumed next iteration
        const int tn = (t + 1 < LSEQ) ? (t + 1) : t;
        float xa_n = x0p[tn];
        float xb_n = x1p[tn];

        // ---- layer 1 gates ----
        float A0[4], A1[4];
#pragma unroll
        for (int m = 0; m < 4; m++) {
            A0[m] = fmaf(xa, wih1r[m], b1r[m]);
            A1[m] = fmaf(xb, wih1r[m], b1r[m]);
        }
#pragma unroll 8
        for (int k = 0; k < H; k++) {
            float4 w = *(const float4*)(whh1 + k * NG);
            float sa = bcast(h1a, k);
            float sb = bcast(h1b, k);
            A0[0] = fmaf(w.x, sa, A0[0]); A0[1] = fmaf(w.y, sa, A0[1]);
            A0[2] = fmaf(w.z, sa, A0[2]); A0[3] = fmaf(w.w, sa, A0[3]);
            A1[0] = fmaf(w.x, sb, A1[0]); A1[1] = fmaf(w.y, sb, A1[1]);
            A1[2] = fmaf(w.z, sb, A1[2]); A1[3] = fmaf(w.w, sb, A1[3]);
        }
        // activations (i=A[0], f=A[1], g=A[2], o=A[3])
        c1a = sigm(A0[1]) * c1a + sigm(A0[0]) * tanh_(A0[2]);
        h1a = sigm(A0[3]) * tanh_(c1a);
        c1b = sigm(A1[1]) * c1b + sigm(A1[0]) * tanh_(A1[2]);
        h1b = sigm(A1[3]) * tanh_(c1b);

        // fence between layers: bounds in-iteration load-burst scheduling
        asm volatile("" ::: "memory");

        // ---- layer 2 gates (two matvecs fused) ----
#pragma unroll
        for (int m = 0; m < 4; m++) { A0[m] = b2r[m]; A1[m] = b2r[m]; }
#pragma unroll 4
        for (int k = 0; k < H; k++) {
            float4 u = *(const float4*)(wih2 + k * NG);
            float4 v = *(const float4*)(whh2 + k * NG);
            float sa = bcast(h1a, k);
            float sb = bcast(h1b, k);
            float ta = bcast(h2a, k);
            float tb = bcast(h2b, k);
            A0[0] = fmaf(u.x, sa, A0[0]); A0[1] = fmaf(u.y, sa, A0[1]);
            A0[2] = fmaf(u.z, sa, A0[2]); A0[3] = fmaf(u.w, sa, A0[3]);
            A0[0] = fmaf(v.x, ta, A0[0]); A0[1] = fmaf(v.y, ta, A0[1]);
            A0[2] = fmaf(v.z, ta, A0[2]); A0[3] = fmaf(v.w, ta, A0[3]);
            A1[0] = fmaf(u.x, sb, A1[0]); A1[1] = fmaf(u.y, sb, A1[1]);
            A1[2] = fmaf(u.z, sb, A1[2]); A1[3] = fmaf(u.w, sb, A1[3]);
            A1[0] = fmaf(v.x, tb, A1[0]); A1[1] = fmaf(v.y, tb, A1[1]);
            A1[2] = fmaf(v.z, tb, A1[2]); A1[3] = fmaf(v.w, tb, A1[3]);
        }
        c2a = sigm(A0[1]) * c2a + sigm(A0[0]) * tanh_(A0[2]);
        h2a = sigm(A0[3]) * tanh_(c2a);
        c2b = sigm(A1[1]) * c2b + sigm(A1[0]) * tanh_(A1[2]);
        h2b = sigm(A1[3]) * tanh_(c2b);

        // ---- output: dot(W_lin, h2_new) + b_lin ----
        float ra = wlinr * h2a;   // lanes >= 51 contribute 0 (wlinr == 0)
        float rb = wlinr * h2b;
#pragma unroll
        for (int off = 32; off >= 1; off >>= 1) {
            ra += __shfl_down(ra, off);
            rb += __shfl_down(rb, off);
        }
        if (lane == 0) {
            o0p[t] = ra + blinv;
            o1p[t] = rb + blinv;
        }

        xa = xa_n;
        xb = xb_n;
    }
}

extern "C" void kernel_launch(void* const* d_in, const int* in_sizes, int n_in,
                              void* d_out, int out_size, void* d_ws, size_t ws_size,
                              hipStream_t stream) {
    const float* x    = (const float*)d_in[0];
    const float* Wih1 = (const float*)d_in[1];
    const float* Whh1 = (const float*)d_in[2];
    const float* bih1 = (const float*)d_in[3];
    const float* bhh1 = (const float*)d_in[4];
    const float* Wih2 = (const float*)d_in[5];
    const float* Whh2 = (const float*)d_in[6];
    const float* bih2 = (const float*)d_in[7];
    const float* bhh2 = (const float*)d_in[8];
    const float* Wlin = (const float*)d_in[9];
    const float* blin = (const float*)d_in[10];
    float* ws  = (float*)d_ws;
    float* out = (float*)d_out;

    hipLaunchKernelGGL(prep_kernel, dim3(4), dim3(256), 0, stream,
                       Wih1, Whh1, bih1, bhh1, Wih2, Whh2, bih2, bhh2, Wlin, blin, ws);

    size_t lds_bytes = (size_t)LDS_DWORDS * 4;
    (void)hipFuncSetAttribute((const void*)lstm_kernel,
                              hipFuncAttributeMaxDynamicSharedMemorySize, (int)lds_bytes);
    hipLaunchKernelGGL(lstm_kernel, dim3(BTOT / 8), dim3(256), lds_bytes, stream,
                       x, ws, out);
}

// Round 4
// 4722.274 us; speedup vs baseline: 14.4659x; 2.4196x over previous
//
#include <hip/hip_runtime.h>
#include <math.h>

#define H 51
#define KROWS 52          // k rows padded (row 51 = zeros)
#define RS 208            // row stride dwords = 52 units * 4 gates (cols 204..207 = zero pad unit)
#define MAT (KROWS * RS)  // 10816 dwords
#define LSEQ 999
#define BTOT 2048

// ws dword offsets
#define OFF_WHH1 0
#define OFF_WIH2 (1 * MAT)
#define OFF_WHH2 (2 * MAT)
#define OFF_VIH1 (3 * MAT)
#define OFF_VB1  (OFF_VIH1 + RS)
#define OFF_VB2  (OFF_VB1 + RS)
#define OFF_VWL  (OFF_VB2 + RS)        // [KROWS] W_lin by unit
#define OFF_VBL  (OFF_VWL + KROWS)

// lds dword offsets
#define L_WHH1 0
#define L_PB1  MAT                     // [4 waves][4 elems][RS] partial gates, layer 1
#define L_PB2  (L_PB1 + 16 * RS)       // same, layer 2
#define L_H1   (L_PB2 + 16 * RS)       // [4 elems][64] h1 vectors
#define L_H2   (L_H1 + 256)            // [4 elems][64] h2 vectors
#define L_TOT  (L_H2 + 256)            // 17984 dw = 71.9 KB  -> 2 blocks/CU

// ---------------- prep: reorder weights, pad k->52 rows and units->52 cols ----------------
// W''[mat][k][u*4+m] = W_orig[m*51+u][k] for k<51,u<51 else 0.  (m: 0=i,1=f,2=g,3=o)
__global__ void prep_kernel(const float* __restrict__ Wih1, const float* __restrict__ Whh1,
                            const float* __restrict__ bih1, const float* __restrict__ bhh1,
                            const float* __restrict__ Wih2, const float* __restrict__ Whh2,
                            const float* __restrict__ bih2, const float* __restrict__ bhh2,
                            const float* __restrict__ Wlin, const float* __restrict__ blin,
                            float* __restrict__ ws) {
    int tid = threadIdx.x + blockIdx.x * blockDim.x;
    int nthr = blockDim.x * gridDim.x;
    for (int idx = tid; idx < 3 * MAT; idx += nthr) {
        int mat = idx / MAT;
        int rem = idx % MAT;
        int k = rem / RS;
        int c = rem % RS;
        int u = c >> 2, m = c & 3;
        float v = 0.0f;
        if (k < H && u < H) {
            const float* W = (mat == 0) ? Whh1 : (mat == 1) ? Wih2 : Whh2;
            v = W[(m * H + u) * H + k];
        }
        ws[mat * MAT + k * RS + c] = v;
    }
    for (int c = tid; c < RS; c += nthr) {
        int u = c >> 2, m = c & 3;
        bool real = (u < H);
        ws[OFF_VIH1 + c] = real ? Wih1[m * H + u] : 0.0f;   // W_ih1 is [204][1]
        ws[OFF_VB1 + c]  = real ? (bih1[m * H + u] + bhh1[m * H + u]) : 0.0f;
        ws[OFF_VB2 + c]  = real ? (bih2[m * H + u] + bhh2[m * H + u]) : 0.0f;
    }
    for (int u = tid; u < KROWS; u += nthr) ws[OFF_VWL + u] = (u < H) ? Wlin[u] : 0.0f;
    if (tid == 0) ws[OFF_VBL] = blin[0];
}

// ---------------- main LSTM kernel ----------------
__device__ __forceinline__ float bcast(float v, int k) {
    return __int_as_float(__builtin_amdgcn_readlane(__float_as_int(v), k));
}
__device__ __forceinline__ float sigm(float x) {
    return __builtin_amdgcn_rcpf(1.0f + __expf(-x));
}
__device__ __forceinline__ float tanh_(float x) {
    return fmaf(-2.0f, __builtin_amdgcn_rcpf(__expf(2.0f * x) + 1.0f), 1.0f);
}

extern __shared__ float lds[];

__global__ void __launch_bounds__(256, 2)
lstm_kernel(const float* __restrict__ x, const float* __restrict__ ws,
            float* __restrict__ out) {
    const int tid = threadIdx.x;
    const int w = tid >> 6;            // wave id = k-quarter owner AND elem owner
    const int j = tid & 63;            // unit lane
    const int cj = (j < H) ? j : H;    // clamp pad lanes to the zero pad unit (col 204)
    const int k0 = w * 13;

    // stage Whh1'' into LDS; zero h buffers
    for (int i = tid; i < MAT; i += 256) lds[i] = ws[i];
    lds[L_H1 + tid] = 0.0f;
    lds[L_H2 + tid] = 0.0f;
    __syncthreads();

    // k-quarter weights for layer 2, register-resident (compile-time indexed)
    float4 wih2r[13], whh2r[13];
#pragma unroll
    for (int kk = 0; kk < 13; kk++) {
        int k = k0 + kk;               // k=51 row is zeros in ws
        wih2r[kk] = *(const float4*)(ws + OFF_WIH2 + k * RS + cj * 4);
        whh2r[kk] = *(const float4*)(ws + OFF_WHH2 + k * RS + cj * 4);
    }
    float wih1r[4], b1r[4], b2r[4];
#pragma unroll
    for (int m = 0; m < 4; m++) {
        wih1r[m] = ws[OFF_VIH1 + cj * 4 + m];
        b1r[m]   = ws[OFF_VB1 + cj * 4 + m];
        b2r[m]   = ws[OFF_VB2 + cj * 4 + m];
    }
    const float wlinr = ws[OFF_VWL + cj];   // 0 for pad lanes
    const float blinv = ws[OFF_VBL];

    const int eo = w;                       // this wave owns elem eo
    const int b0 = blockIdx.x * 4;
    const float* xp = x + (size_t)(b0 + eo) * LSEQ;
    float* op = out + (size_t)(b0 + eo) * LSEQ;

    float h1r[4] = {0.f, 0.f, 0.f, 0.f};
    float h2r[4] = {0.f, 0.f, 0.f, 0.f};
    float c1 = 0.f, c2 = 0.f;
    float xcur = xp[0];

    for (int t = 0; t < LSEQ; t++) {
        float xnext = xp[(t + 1 < LSEQ) ? t + 1 : t];

        // ---- layer 1 partials over own k-quarter ----
        float A[4][4];
#pragma unroll
        for (int e = 0; e < 4; e++)
#pragma unroll
            for (int m = 0; m < 4; m++) A[e][m] = 0.0f;
#pragma unroll
        for (int kk = 0; kk < 13; kk++) {
            const float4 wv = *(const float4*)(lds + L_WHH1 + (k0 + kk) * RS + cj * 4);
#pragma unroll
            for (int e = 0; e < 4; e++) {
                const float s = bcast(h1r[e], k0 + kk);
                A[e][0] = fmaf(wv.x, s, A[e][0]);
                A[e][1] = fmaf(wv.y, s, A[e][1]);
                A[e][2] = fmaf(wv.z, s, A[e][2]);
                A[e][3] = fmaf(wv.w, s, A[e][3]);
            }
        }
#pragma unroll
        for (int e = 0; e < 4; e++)
            *(float4*)(lds + L_PB1 + (w * 4 + e) * RS + cj * 4) =
                make_float4(A[e][0], A[e][1], A[e][2], A[e][3]);
        __syncthreads();
        asm volatile("" ::: "memory");

        // ---- reduce + activations for OWN elem only (single producer => deterministic) ----
        {
            const float4 P0 = *(const float4*)(lds + L_PB1 + (0 * 4 + eo) * RS + cj * 4);
            const float4 P1 = *(const float4*)(lds + L_PB1 + (1 * 4 + eo) * RS + cj * 4);
            const float4 P2 = *(const float4*)(lds + L_PB1 + (2 * 4 + eo) * RS + cj * 4);
            const float4 P3 = *(const float4*)(lds + L_PB1 + (3 * 4 + eo) * RS + cj * 4);
            const float g0 = ((P0.x + P1.x) + (P2.x + P3.x)) + fmaf(xcur, wih1r[0], b1r[0]);
            const float g1 = ((P0.y + P1.y) + (P2.y + P3.y)) + fmaf(xcur, wih1r[1], b1r[1]);
            const float g2 = ((P0.z + P1.z) + (P2.z + P3.z)) + fmaf(xcur, wih1r[2], b1r[2]);
            const float g3 = ((P0.w + P1.w) + (P2.w + P3.w)) + fmaf(xcur, wih1r[3], b1r[3]);
            c1 = sigm(g1) * c1 + sigm(g0) * tanh_(g2);
            const float h1n = sigm(g3) * tanh_(c1);
            lds[L_H1 + eo * 64 + j] = h1n;
        }
        __syncthreads();
        asm volatile("" ::: "memory");

        // refresh replicated h state (h2 here is still step t-1's value)
#pragma unroll
        for (int e = 0; e < 4; e++) {
            h1r[e] = lds[L_H1 + e * 64 + j];
            h2r[e] = lds[L_H2 + e * 64 + j];
        }

        // ---- layer 2 partials over own k-quarter (weights in registers) ----
#pragma unroll
        for (int e = 0; e < 4; e++)
#pragma unroll
            for (int m = 0; m < 4; m++) A[e][m] = 0.0f;
#pragma unroll
        for (int kk = 0; kk < 13; kk++) {
            const float4 u = wih2r[kk];
            const float4 v = whh2r[kk];
#pragma unroll
            for (int e = 0; e < 4; e++) {
                const float s1 = bcast(h1r[e], k0 + kk);
                const float s2 = bcast(h2r[e], k0 + kk);
                A[e][0] = fmaf(u.x, s1, A[e][0]); A[e][0] = fmaf(v.x, s2, A[e][0]);
                A[e][1] = fmaf(u.y, s1, A[e][1]); A[e][1] = fmaf(v.y, s2, A[e][1]);
                A[e][2] = fmaf(u.z, s1, A[e][2]); A[e][2] = fmaf(v.z, s2, A[e][2]);
                A[e][3] = fmaf(u.w, s1, A[e][3]); A[e][3] = fmaf(v.w, s2, A[e][3]);
            }
        }
#pragma unroll
        for (int e = 0; e < 4; e++)
            *(float4*)(lds + L_PB2 + (w * 4 + e) * RS + cj * 4) =
                make_float4(A[e][0], A[e][1], A[e][2], A[e][3]);
        __syncthreads();
        asm volatile("" ::: "memory");

        // ---- reduce + activations + output for OWN elem ----
        {
            const float4 P0 = *(const float4*)(lds + L_PB2 + (0 * 4 + eo) * RS + cj * 4);
            const float4 P1 = *(const float4*)(lds + L_PB2 + (1 * 4 + eo) * RS + cj * 4);
            const float4 P2 = *(const float4*)(lds + L_PB2 + (2 * 4 + eo) * RS + cj * 4);
            const float4 P3 = *(const float4*)(lds + L_PB2 + (3 * 4 + eo) * RS + cj * 4);
            const float g0 = ((P0.x + P1.x) + (P2.x + P3.x)) + b2r[0];
            const float g1 = ((P0.y + P1.y) + (P2.y + P3.y)) + b2r[1];
            const float g2 = ((P0.z + P1.z) + (P2.z + P3.z)) + b2r[2];
            const float g3 = ((P0.w + P1.w) + (P2.w + P3.w)) + b2r[3];
            c2 = sigm(g1) * c2 + sigm(g0) * tanh_(g2);
            const float h2n = sigm(g3) * tanh_(c2);

            float r = wlinr * h2n;   // pad lanes contribute 0
#pragma unroll
            for (int off = 32; off >= 1; off >>= 1) r += __shfl_down(r, off);
            if (j == 0) op[t] = r + blinv;

            lds[L_H2 + eo * 64 + j] = h2n;   // consumed after next step's B1+B2
        }

        xcur = xnext;
    }
}

extern "C" void kernel_launch(void* const* d_in, const int* in_sizes, int n_in,
                              void* d_out, int out_size, void* d_ws, size_t ws_size,
                              hipStream_t stream) {
    const float* x    = (const float*)d_in[0];
    const float* Wih1 = (const float*)d_in[1];
    const float* Whh1 = (const float*)d_in[2];
    const float* bih1 = (const float*)d_in[3];
    const float* bhh1 = (const float*)d_in[4];
    const float* Wih2 = (const float*)d_in[5];
    const float* Whh2 = (const float*)d_in[6];
    const float* bih2 = (const float*)d_in[7];
    const float* bhh2 = (const float*)d_in[8];
    const float* Wlin = (const float*)d_in[9];
    const float* blin = (const float*)d_in[10];
    float* ws  = (float*)d_ws;
    float* out = (float*)d_out;

    hipLaunchKernelGGL(prep_kernel, dim3(32), dim3(256), 0, stream,
                       Wih1, Whh1, bih1, bhh1, Wih2, Whh2, bih2, bhh2, Wlin, blin, ws);

    size_t lds_bytes = (size_t)L_TOT * 4;
    (void)hipFuncSetAttribute((const void*)lstm_kernel,
                              hipFuncAttributeMaxDynamicSharedMemorySize, (int)lds_bytes);
    hipLaunchKernelGGL(lstm_kernel, dim3(BTOT / 4), dim3(256), lds_bytes, stream,
                       x, ws, out);
}

// Round 5
// 1645.799 us; speedup vs baseline: 41.5067x; 2.8693x over previous
//
#include <hip/hip_runtime.h>
#include <math.h>

#define H 51
#define LSEQ 999
#define BTOT 2048
#define E 16
#define NBLK (BTOT / E)     // 128 blocks

#define ROWS 256            // 64 units * 4 gates (unit-major rows: row = u*4+m)
#define K1 64               // layer1 K: k=0..50 h1, k=63 x, rest zero
#define K2 128              // layer2 K: k=0..50 h1, k=64..114 h2, rest zero

// ws float offsets
#define WS_W1 0
#define WS_W2 (WS_W1 + ROWS * K1)
#define WS_B1 (WS_W2 + ROWS * K2)
#define WS_B2 (WS_B1 + ROWS)
#define WS_WL (WS_B2 + ROWS)
#define WS_BL (WS_WL + 64)

// LDS frames: 1 frame = one 32-K B-fragment plane (64 lanes x 16B)
#define FRAME 1024
#define NFRAMES 20
#define PART_OFF (NFRAMES * FRAME)
#define LDS_BYTES (PART_OFF + 64 * 4)

// frame ids (hi plane; lo plane = +1)
#define F_L1(b, s)   (((b) * 2 + (s)) * 2)       // layer1 B, double-buffered: 0..7
#define F_L2H1(s)    (8 + (s) * 2)               // layer2 h1 zone (single): 8..11
#define F_L2H2(b, s) (12 + ((b) * 2 + (s)) * 2)  // layer2 h2 zone, double-buffered: 12..19

typedef __attribute__((ext_vector_type(8))) short bf16x8;
typedef __attribute__((ext_vector_type(4))) float f32x4;

// ---------------- prep: padded cat-matrices, unit-major rows ----------------
__global__ void prep_kernel(const float* __restrict__ Wih1, const float* __restrict__ Whh1,
                            const float* __restrict__ bih1, const float* __restrict__ bhh1,
                            const float* __restrict__ Wih2, const float* __restrict__ Whh2,
                            const float* __restrict__ bih2, const float* __restrict__ bhh2,
                            const float* __restrict__ Wlin, const float* __restrict__ blin,
                            float* __restrict__ ws) {
    int tid = threadIdx.x + blockIdx.x * blockDim.x;
    int nthr = blockDim.x * gridDim.x;
    for (int idx = tid; idx < ROWS * K1; idx += nthr) {
        int R = idx / K1, k = idx % K1;
        int u = R >> 2, m = R & 3;
        float v = 0.0f;
        if (u < H) {
            if (k < H) v = Whh1[(m * H + u) * H + k];
            else if (k == 63) v = Wih1[m * H + u];   // Wih1 is [204][1]
        }
        ws[WS_W1 + idx] = v;
    }
    for (int idx = tid; idx < ROWS * K2; idx += nthr) {
        int R = idx / K2, k = idx % K2;
        int u = R >> 2, m = R & 3;
        float v = 0.0f;
        if (u < H) {
            if (k < H) v = Wih2[(m * H + u) * H + k];
            else if (k >= 64 && k < 64 + H) v = Whh2[(m * H + u) * H + (k - 64)];
        }
        ws[WS_W2 + idx] = v;
    }
    for (int R = tid; R < ROWS; R += nthr) {
        int u = R >> 2, m = R & 3;
        float v1 = 0.0f, v2 = 0.0f;
        if (u < H) {
            v1 = bih1[m * H + u] + bhh1[m * H + u];
            v2 = bih2[m * H + u] + bhh2[m * H + u];
        }
        ws[WS_B1 + R] = v1;
        ws[WS_B2 + R] = v2;
    }
    for (int u = tid; u < 64; u += nthr) ws[WS_WL + u] = (u < H) ? Wlin[u] : 0.0f;
    if (tid == 0) ws[WS_BL] = blin[0];
}

// ---------------- helpers ----------------
__device__ __forceinline__ short f2bf(float f) {      // round-to-nearest-even
    unsigned u = __float_as_uint(f);
    unsigned r = (u + 0x7fffu + ((u >> 16) & 1u)) >> 16;
    return (short)r;
}
__device__ __forceinline__ float bf2f(short b) {
    return __uint_as_float(((unsigned)(unsigned short)b) << 16);
}
__device__ __forceinline__ float sigm(float x) {
    return __builtin_amdgcn_rcpf(1.0f + __expf(-x));
}
__device__ __forceinline__ float tanh_(float x) {
    return fmaf(-2.0f, __builtin_amdgcn_rcpf(__expf(2.0f * x) + 1.0f), 1.0f);
}
// scatter one h value into B-fragment layout: elems 0..3 <-> k=4g+j, 4..7 <-> 16+4g+j
__device__ __forceinline__ void wr_h(char* base, int fhi, int k, int e, short hi, short lo) {
    const int kk = k & 31;
    const int gg = (kk & 15) >> 2;
    const int j  = (kk & 3) + ((kk >> 4) << 2);
    const int off = (gg * 16 + e) * 16 + j * 2;
    *(short*)(base + (size_t)fhi * FRAME + off) = hi;
    *(short*)(base + (size_t)(fhi + 1) * FRAME + off) = lo;
}
__device__ __forceinline__ bf16x8 ld_fr(const char* base, int f, int l) {
    return *(const bf16x8*)(base + (size_t)f * FRAME + (size_t)l * 16);
}

// ---------------- main LSTM kernel ----------------
__global__ void __launch_bounds__(256, 1)
lstm_kernel(const float* __restrict__ x, const float* __restrict__ ws,
            float* __restrict__ out) {
    __shared__ __align__(16) char smem[LDS_BYTES];

    const int tid = threadIdx.x;
    const int w = tid >> 6;
    const int l = tid & 63;
    const int g = l >> 4;
    const int e = l & 15;

    for (int i = tid; i < LDS_BYTES / 4; i += 256) ((float*)smem)[i] = 0.0f;

    // ---- prologue: register-resident W fragments (hi/lo bf16 split) ----
    bf16x8 w1h[4][2], w1l[4][2], w2h[4][4], w2l[4][4];
    f32x4 b1v[4], b2v[4];
    float wlr[4];
#pragma unroll
    for (int i = 0; i < 4; ++i) {
        const int T = w * 4 + i;
        const int rowA = T * 16 + (l & 15);
#pragma unroll
        for (int s = 0; s < 2; ++s) {
            bf16x8 hh, ll;
#pragma unroll
            for (int j = 0; j < 8; ++j) {
                const int k = s * 32 + ((j < 4) ? (4 * g + j) : (16 + 4 * g + (j - 4)));
                float wv = ws[WS_W1 + rowA * K1 + k];
                short hb = f2bf(wv);
                hh[j] = hb;
                ll[j] = f2bf(wv - bf2f(hb));
            }
            w1h[i][s] = hh; w1l[i][s] = ll;
        }
#pragma unroll
        for (int s = 0; s < 4; ++s) {
            bf16x8 hh, ll;
#pragma unroll
            for (int j = 0; j < 8; ++j) {
                const int k = s * 32 + ((j < 4) ? (4 * g + j) : (16 + 4 * g + (j - 4)));
                float wv = ws[WS_W2 + rowA * K2 + k];
                short hb = f2bf(wv);
                hh[j] = hb;
                ll[j] = f2bf(wv - bf2f(hb));
            }
            w2h[i][s] = hh; w2l[i][s] = ll;
        }
#pragma unroll
        for (int r = 0; r < 4; ++r) {
            b1v[i][r] = ws[WS_B1 + T * 16 + 4 * g + r];
            b2v[i][r] = ws[WS_B2 + T * 16 + 4 * g + r];
        }
        wlr[i] = ws[WS_WL + T * 4 + g];
    }
    const float blv = ws[WS_BL];

    const int b0 = blockIdx.x * E;
    const float* xp = x + (size_t)(b0 + e) * LSEQ;   // used by wave0 lanes<16 only
    float xv = 0.0f;
    if (w == 0 && l < 16) {
        float x0 = xp[0];
        short hb = f2bf(x0);
        wr_h(smem, F_L1(0, 1), 63, e, hb, f2bf(x0 - bf2f(hb)));   // x[0] -> buf0 k=63
        xv = xp[1];
    }

    float c1s[4] = {0.f, 0.f, 0.f, 0.f};
    float c2s[4] = {0.f, 0.f, 0.f, 0.f};

    __syncthreads();

    // preload L1 B-frags for t=0 (buf 0: zeros + x[0])
    bf16x8 a1h[2], a1l[2];
#pragma unroll
    for (int s = 0; s < 2; ++s) {
        a1h[s] = ld_fr(smem, F_L1(0, s), l);
        a1l[s] = ld_fr(smem, F_L1(0, s) + 1, l);
    }

    for (int t = 0; t < LSEQ; ++t) {
        const int p = t & 1;

        // preload h2-prev frags (written at t-1 phase2, visible after end-barrier)
        bf16x8 h2h[2], h2l[2];
#pragma unroll
        for (int s = 0; s < 2; ++s) {
            h2h[s] = ld_fr(smem, F_L2H2(p, s), l);
            h2l[s] = ld_fr(smem, F_L2H2(p, s) + 1, l);
        }

        // output for step t-1 (partials written at t-1 phase2)
        if (w == 1 && l < 16 && t > 0) {
            const float* pp = (const float*)(smem + PART_OFF);
            out[(size_t)(b0 + l) * LSEQ + (t - 1)] =
                ((pp[l] + pp[16 + l]) + (pp[32 + l] + pp[48 + l])) + blv;
        }

        // write x[t+1] into next L1 buf; prefetch x[t+2]
        float xnew = 0.0f;
        if (w == 0 && l < 16) {
            xnew = xp[(t + 2 < LSEQ) ? (t + 2) : (LSEQ - 1)];
            short hb = f2bf(xv);
            wr_h(smem, F_L1(p ^ 1, 1), 63, e, hb, f2bf(xv - bf2f(hb)));
        }

        // ---- layer 1: gates = W1cat x [h1_prev; x] ----
        f32x4 acc[4];
#pragma unroll
        for (int i = 0; i < 4; ++i) acc[i] = b1v[i];
#pragma unroll
        for (int s = 0; s < 2; ++s)
#pragma unroll
            for (int i = 0; i < 4; ++i) {
                acc[i] = __builtin_amdgcn_mfma_f32_16x16x32_bf16(w1h[i][s], a1h[s], acc[i], 0, 0, 0);
                acc[i] = __builtin_amdgcn_mfma_f32_16x16x32_bf16(w1h[i][s], a1l[s], acc[i], 0, 0, 0);
                acc[i] = __builtin_amdgcn_mfma_f32_16x16x32_bf16(w1l[i][s], a1h[s], acc[i], 0, 0, 0);
            }

        // activations (lane-local: 4 regs = i,f,g,o of unit u, elem e) + h1 scatter
#pragma unroll
        for (int i = 0; i < 4; ++i) {
            float ig = sigm(acc[i][0]), fg = sigm(acc[i][1]);
            float gg = tanh_(acc[i][2]), og = sigm(acc[i][3]);
            c1s[i] = fg * c1s[i] + ig * gg;
            float h1 = og * tanh_(c1s[i]);
            short hb = f2bf(h1);
            short lb = f2bf(h1 - bf2f(hb));
            const int u = (w * 4 + i) * 4 + g;
            if (u < 63) wr_h(smem, F_L1(p ^ 1, u >> 5), u, e, hb, lb);  // k=63 is x's slot
            wr_h(smem, F_L2H1(u >> 5), u, e, hb, lb);
        }

        __syncthreads();

        // load h1-cur frags (written this step, pre-barrier)
        bf16x8 h1h[2], h1l[2];
#pragma unroll
        for (int s = 0; s < 2; ++s) {
            h1h[s] = ld_fr(smem, F_L2H1(s), l);
            h1l[s] = ld_fr(smem, F_L2H1(s) + 1, l);
        }

        // ---- layer 2: gates = W2cat x [h1_cur; h2_prev] ----
#pragma unroll
        for (int i = 0; i < 4; ++i) acc[i] = b2v[i];
#pragma unroll
        for (int s = 0; s < 4; ++s) {
            const bf16x8 bh = (s < 2) ? h1h[s & 1] : h2h[s & 1];
            const bf16x8 bl = (s < 2) ? h1l[s & 1] : h2l[s & 1];
#pragma unroll
            for (int i = 0; i < 4; ++i) {
                acc[i] = __builtin_amdgcn_mfma_f32_16x16x32_bf16(w2h[i][s], bh, acc[i], 0, 0, 0);
                acc[i] = __builtin_amdgcn_mfma_f32_16x16x32_bf16(w2h[i][s], bl, acc[i], 0, 0, 0);
                acc[i] = __builtin_amdgcn_mfma_f32_16x16x32_bf16(w2l[i][s], bh, acc[i], 0, 0, 0);
            }
        }

        // activations + h2 scatter + output partial
        float pr = 0.0f;
#pragma unroll
        for (int i = 0; i < 4; ++i) {
            float ig = sigm(acc[i][0]), fg = sigm(acc[i][1]);
            float gg = tanh_(acc[i][2]), og = sigm(acc[i][3]);
            c2s[i] = fg * c2s[i] + ig * gg;
            float h2 = og * tanh_(c2s[i]);
            short hb = f2bf(h2);
            short lb = f2bf(h2 - bf2f(hb));
            const int u = (w * 4 + i) * 4 + g;
            wr_h(smem, F_L2H2(p ^ 1, u >> 5), 64 + u, e, hb, lb);
            pr = fmaf(wlr[i], h2, pr);
        }
        pr += __shfl_xor(pr, 16);
        pr += __shfl_xor(pr, 32);
        if (l < 16) *(float*)(smem + PART_OFF + (size_t)(w * 16 + l) * 4) = pr;

        // preload next step's L1 frags (buf p^1: h1 + x written pre-mid-barrier)
#pragma unroll
        for (int s = 0; s < 2; ++s) {
            a1h[s] = ld_fr(smem, F_L1(p ^ 1, s), l);
            a1l[s] = ld_fr(smem, F_L1(p ^ 1, s) + 1, l);
        }

        __syncthreads();
        xv = xnew;
    }

    // final output (t = LSEQ-1)
    if (w == 1 && l < 16) {
        const float* pp = (const float*)(smem + PART_OFF);
        out[(size_t)(b0 + l) * LSEQ + (LSEQ - 1)] =
            ((pp[l] + pp[16 + l]) + (pp[32 + l] + pp[48 + l])) + blv;
    }
}

extern "C" void kernel_launch(void* const* d_in, const int* in_sizes, int n_in,
                              void* d_out, int out_size, void* d_ws, size_t ws_size,
                              hipStream_t stream) {
    const float* x    = (const float*)d_in[0];
    const float* Wih1 = (const float*)d_in[1];
    const float* Whh1 = (const float*)d_in[2];
    const float* bih1 = (const float*)d_in[3];
    const float* bhh1 = (const float*)d_in[4];
    const float* Wih2 = (const float*)d_in[5];
    const float* Whh2 = (const float*)d_in[6];
    const float* bih2 = (const float*)d_in[7];
    const float* bhh2 = (const float*)d_in[8];
    const float* Wlin = (const float*)d_in[9];
    const float* blin = (const float*)d_in[10];
    float* ws  = (float*)d_ws;
    float* out = (float*)d_out;

    hipLaunchKernelGGL(prep_kernel, dim3(64), dim3(256), 0, stream,
                       Wih1, Whh1, bih1, bhh1, Wih2, Whh2, bih2, bhh2, Wlin, blin, ws);
    hipLaunchKernelGGL(lstm_kernel, dim3(NBLK), dim3(256), 0, stream, x, ws, out);
}

// Round 6
// 1278.266 us; speedup vs baseline: 53.4409x; 1.2875x over previous
//
#include <hip/hip_runtime.h>
#include <math.h>

#define H 51
#define LSEQ 999
#define BTOT 2048
#define E 16
#define NBLK (BTOT / E)     // 128 blocks

#define ROWS 256            // 64 units * 4 gates (unit-major rows: row = u*4+m)
#define K1 64               // layer1 K: k=0..50 h1, k=63 x, rest zero
#define K2 128              // layer2 K: k=0..50 h1 (k=63 x slot, W2 col = 0), k=64..114 h2

// ws float offsets
#define WS_W1 0
#define WS_W2 (WS_W1 + ROWS * K1)
#define WS_B1 (WS_W2 + ROWS * K2)
#define WS_B2 (WS_B1 + ROWS)
#define WS_WL (WS_B2 + ROWS)
#define WS_BL (WS_WL + 64)

// LDS frames: 1 frame = one 32-K B-fragment plane (64 lanes x 16B)
#define FRAME 1024
#define NFRAMES 16
#define PART_OFF (NFRAMES * FRAME)
#define LDS_BYTES (PART_OFF + 8 * 16 * 4)

// frame ids (hi plane; lo plane = +1)
#define F_L1(b, s) (((b) * 2 + (s)) * 2)       // layer1/L2-h1 B, double-buffered: 0..7
#define F_H2(b, s) (8 + ((b) * 2 + (s)) * 2)   // layer2 h2 zone, double-buffered: 8..15

typedef __attribute__((ext_vector_type(8))) short bf16x8;
typedef __attribute__((ext_vector_type(4))) float f32x4;

// ---------------- prep: padded cat-matrices, unit-major rows ----------------
__global__ void prep_kernel(const float* __restrict__ Wih1, const float* __restrict__ Whh1,
                            const float* __restrict__ bih1, const float* __restrict__ bhh1,
                            const float* __restrict__ Wih2, const float* __restrict__ Whh2,
                            const float* __restrict__ bih2, const float* __restrict__ bhh2,
                            const float* __restrict__ Wlin, const float* __restrict__ blin,
                            float* __restrict__ ws) {
    int tid = threadIdx.x + blockIdx.x * blockDim.x;
    int nthr = blockDim.x * gridDim.x;
    for (int idx = tid; idx < ROWS * K1; idx += nthr) {
        int R = idx / K1, k = idx % K1;
        int u = R >> 2, m = R & 3;
        float v = 0.0f;
        if (u < H) {
            if (k < H) v = Whh1[(m * H + u) * H + k];
            else if (k == 63) v = Wih1[m * H + u];   // Wih1 is [204][1]
        }
        ws[WS_W1 + idx] = v;
    }
    for (int idx = tid; idx < ROWS * K2; idx += nthr) {
        int R = idx / K2, k = idx % K2;
        int u = R >> 2, m = R & 3;
        float v = 0.0f;
        if (u < H) {
            if (k < H) v = Wih2[(m * H + u) * H + k];
            else if (k >= 64 && k < 64 + H) v = Whh2[(m * H + u) * H + (k - 64)];
        }
        ws[WS_W2 + idx] = v;
    }
    for (int R = tid; R < ROWS; R += nthr) {
        int u = R >> 2, m = R & 3;
        float v1 = 0.0f, v2 = 0.0f;
        if (u < H) {
            v1 = bih1[m * H + u] + bhh1[m * H + u];
            v2 = bih2[m * H + u] + bhh2[m * H + u];
        }
        ws[WS_B1 + R] = v1;
        ws[WS_B2 + R] = v2;
    }
    for (int u = tid; u < 64; u += nthr) ws[WS_WL + u] = (u < H) ? Wlin[u] : 0.0f;
    if (tid == 0) ws[WS_BL] = blin[0];
}

// ---------------- helpers ----------------
__device__ __forceinline__ short f2bf(float f) {      // round-to-nearest-even
    unsigned u = __float_as_uint(f);
    unsigned r = (u + 0x7fffu + ((u >> 16) & 1u)) >> 16;
    return (short)r;
}
__device__ __forceinline__ float bf2f(short b) {
    return __uint_as_float(((unsigned)(unsigned short)b) << 16);
}
__device__ __forceinline__ float sigm(float x) {
    return __builtin_amdgcn_rcpf(1.0f + __expf(-x));
}
__device__ __forceinline__ float tanh_(float x) {
    return fmaf(-2.0f, __builtin_amdgcn_rcpf(__expf(2.0f * x) + 1.0f), 1.0f);
}
// scatter one h value into B-fragment layout: elems 0..3 <-> k=4g+j, 4..7 <-> 16+4g+j
__device__ __forceinline__ void wr_h(char* base, int fhi, int k, int e, short hi, short lo) {
    const int kk = k & 31;
    const int gg = (kk & 15) >> 2;
    const int j  = (kk & 3) + ((kk >> 4) << 2);
    const int off = (gg * 16 + e) * 16 + j * 2;
    *(short*)(base + (size_t)fhi * FRAME + off) = hi;
    *(short*)(base + (size_t)(fhi + 1) * FRAME + off) = lo;
}
__device__ __forceinline__ bf16x8 ld_fr(const char* base, int f, int l) {
    return *(const bf16x8*)(base + (size_t)f * FRAME + (size_t)l * 16);
}

// ---------------- main LSTM kernel ----------------
__global__ void __launch_bounds__(512, 1)
lstm_kernel(const float* __restrict__ x, const float* __restrict__ ws,
            float* __restrict__ out) {
    __shared__ __align__(16) char smem[LDS_BYTES];

    const int tid = threadIdx.x;
    const int w = tid >> 6;        // 0..7; each wave owns 2 row-tiles T = w*2+i
    const int l = tid & 63;
    const int g = l >> 4;
    const int e = l & 15;

    for (int i = tid; i < LDS_BYTES / 4; i += 512) ((float*)smem)[i] = 0.0f;

    // ---- prologue: register-resident W fragments (hi/lo bf16 split) ----
    bf16x8 w1h[2][2], w1l[2][2], w2h[2][4], w2l[2][4];
    f32x4 b1v[2], b2v[2];
    float wlr[2];
#pragma unroll
    for (int i = 0; i < 2; ++i) {
        const int T = w * 2 + i;
        const int rowA = T * 16 + e;
#pragma unroll
        for (int s = 0; s < 2; ++s) {
            bf16x8 hh, ll;
#pragma unroll
            for (int j = 0; j < 8; ++j) {
                const int k = s * 32 + ((j < 4) ? (4 * g + j) : (16 + 4 * g + (j - 4)));
                float wv = ws[WS_W1 + rowA * K1 + k];
                short hb = f2bf(wv);
                hh[j] = hb;
                ll[j] = f2bf(wv - bf2f(hb));
            }
            w1h[i][s] = hh; w1l[i][s] = ll;
        }
#pragma unroll
        for (int s = 0; s < 4; ++s) {
            bf16x8 hh, ll;
#pragma unroll
            for (int j = 0; j < 8; ++j) {
                const int k = s * 32 + ((j < 4) ? (4 * g + j) : (16 + 4 * g + (j - 4)));
                float wv = ws[WS_W2 + rowA * K2 + k];
                short hb = f2bf(wv);
                hh[j] = hb;
                ll[j] = f2bf(wv - bf2f(hb));
            }
            w2h[i][s] = hh; w2l[i][s] = ll;
        }
#pragma unroll
        for (int r = 0; r < 4; ++r) {
            b1v[i][r] = ws[WS_B1 + T * 16 + 4 * g + r];
            b2v[i][r] = ws[WS_B2 + T * 16 + 4 * g + r];
        }
        wlr[i] = ws[WS_WL + T * 4 + g];
    }
    const float blv = ws[WS_BL];

    const int b0 = blockIdx.x * E;
    const float* xp = x + (size_t)(b0 + e) * LSEQ;   // used by wave0 lanes<16 only
    float* pparts = (float*)(smem + PART_OFF);

    __syncthreads();   // zero-init complete

    float xv = 0.0f;
    if (w == 0 && l < 16) {
        float x0 = xp[0];
        short hb = f2bf(x0);
        wr_h(smem, F_L1(0, 1), 63, e, hb, f2bf(x0 - bf2f(hb)));   // x[0] -> buf0 k=63
        xv = xp[1];
    }

    float c1s[2] = {0.f, 0.f};
    float c2s[2] = {0.f, 0.f};

    __syncthreads();   // x[0] visible

    // a1 = L1 B-frags for t=0 (buf 0: zeros + x[0]); also serve L2 k=0..63 of each step
    bf16x8 a1h[2], a1l[2];
#pragma unroll
    for (int s = 0; s < 2; ++s) {
        a1h[s] = ld_fr(smem, F_L1(0, s), l);
        a1l[s] = ld_fr(smem, F_L1(0, s) + 1, l);
    }

    for (int t = 0; t < LSEQ; ++t) {
        const int p = t & 1;

        // h2-prev frags (written at t-1 phase2 into F_H2(p), end-barrier ordered)
        bf16x8 h2h[2], h2l[2];
#pragma unroll
        for (int s = 0; s < 2; ++s) {
            h2h[s] = ld_fr(smem, F_H2(p, s), l);
            h2l[s] = ld_fr(smem, F_H2(p, s) + 1, l);
        }

        // output for step t-1 (partials written at t-1 phase2)
        if (w == 1 && l < 16 && t > 0) {
            float r = ((pparts[l] + pparts[16 + l]) + (pparts[32 + l] + pparts[48 + l])) +
                      ((pparts[64 + l] + pparts[80 + l]) + (pparts[96 + l] + pparts[112 + l]));
            out[(size_t)(b0 + l) * LSEQ + (t - 1)] = r + blv;
        }

        // write x[t+1] into next L1 buf; prefetch x[t+2]
        float xnew = 0.0f;
        if (w == 0 && l < 16) {
            xnew = xp[(t + 2 < LSEQ) ? (t + 2) : (LSEQ - 1)];
            short hb = f2bf(xv);
            wr_h(smem, F_L1(p ^ 1, 1), 63, e, hb, f2bf(xv - bf2f(hb)));
        }

        // ---- pre-barrier MFMAs: L1 (h1_prev, x) and L2's h2-half — independent chains ----
        f32x4 acc1[2], acc2[2];
#pragma unroll
        for (int i = 0; i < 2; ++i) { acc1[i] = b1v[i]; acc2[i] = b2v[i]; }
#pragma unroll
        for (int s = 0; s < 2; ++s)
#pragma unroll
            for (int i = 0; i < 2; ++i) {
                acc1[i] = __builtin_amdgcn_mfma_f32_16x16x32_bf16(w1h[i][s], a1h[s], acc1[i], 0, 0, 0);
                acc2[i] = __builtin_amdgcn_mfma_f32_16x16x32_bf16(w2h[i][s + 2], h2h[s], acc2[i], 0, 0, 0);
                acc1[i] = __builtin_amdgcn_mfma_f32_16x16x32_bf16(w1h[i][s], a1l[s], acc1[i], 0, 0, 0);
                acc2[i] = __builtin_amdgcn_mfma_f32_16x16x32_bf16(w2h[i][s + 2], h2l[s], acc2[i], 0, 0, 0);
                acc1[i] = __builtin_amdgcn_mfma_f32_16x16x32_bf16(w1l[i][s], a1h[s], acc1[i], 0, 0, 0);
                acc2[i] = __builtin_amdgcn_mfma_f32_16x16x32_bf16(w2l[i][s + 2], h2h[s], acc2[i], 0, 0, 0);
            }

        // layer-1 activations (lane-local) + h1 scatter into F_L1(p^1)
#pragma unroll
        for (int i = 0; i < 2; ++i) {
            float ig = sigm(acc1[i][0]), fg = sigm(acc1[i][1]);
            float gg = tanh_(acc1[i][2]), og = sigm(acc1[i][3]);
            c1s[i] = fg * c1s[i] + ig * gg;
            float h1 = og * tanh_(c1s[i]);
            short hb = f2bf(h1);
            short lb = f2bf(h1 - bf2f(hb));
            const int u = (w * 2 + i) * 4 + g;
            if (u < 63) wr_h(smem, F_L1(p ^ 1, u >> 5), u, e, hb, lb);  // k=63 is x's slot
        }

        __syncthreads();

        // combined load: L2's k=0..63 B-frags == next step's L1 frags (W2 col 63 = 0)
#pragma unroll
        for (int s = 0; s < 2; ++s) {
            a1h[s] = ld_fr(smem, F_L1(p ^ 1, s), l);
            a1l[s] = ld_fr(smem, F_L1(p ^ 1, s) + 1, l);
        }

        // ---- layer 2, h1-half ----
#pragma unroll
        for (int s = 0; s < 2; ++s)
#pragma unroll
            for (int i = 0; i < 2; ++i) {
                acc2[i] = __builtin_amdgcn_mfma_f32_16x16x32_bf16(w2h[i][s], a1h[s], acc2[i], 0, 0, 0);
                acc2[i] = __builtin_amdgcn_mfma_f32_16x16x32_bf16(w2h[i][s], a1l[s], acc2[i], 0, 0, 0);
                acc2[i] = __builtin_amdgcn_mfma_f32_16x16x32_bf16(w2l[i][s], a1h[s], acc2[i], 0, 0, 0);
            }

        // layer-2 activations + h2 scatter + output partial
        float pr = 0.0f;
#pragma unroll
        for (int i = 0; i < 2; ++i) {
            float ig = sigm(acc2[i][0]), fg = sigm(acc2[i][1]);
            float gg = tanh_(acc2[i][2]), og = sigm(acc2[i][3]);
            c2s[i] = fg * c2s[i] + ig * gg;
            float h2 = og * tanh_(c2s[i]);
            short hb = f2bf(h2);
            short lb = f2bf(h2 - bf2f(hb));
            const int u = (w * 2 + i) * 4 + g;
            wr_h(smem, F_H2(p ^ 1, u >> 5), 64 + u, e, hb, lb);
            pr = fmaf(wlr[i], h2, pr);
        }
        pr += __shfl_xor(pr, 16);
        pr += __shfl_xor(pr, 32);
        if (l < 16) pparts[w * 16 + l] = pr;

        __syncthreads();
        xv = xnew;
    }

    // final output (t = LSEQ-1)
    if (w == 1 && l < 16) {
        float r = ((pparts[l] + pparts[16 + l]) + (pparts[32 + l] + pparts[48 + l])) +
                  ((pparts[64 + l] + pparts[80 + l]) + (pparts[96 + l] + pparts[112 + l]));
        out[(size_t)(b0 + l) * LSEQ + (LSEQ - 1)] = r + blv;
    }
}

extern "C" void kernel_launch(void* const* d_in, const int* in_sizes, int n_in,
                              void* d_out, int out_size, void* d_ws, size_t ws_size,
                              hipStream_t stream) {
    const float* x    = (const float*)d_in[0];
    const float* Wih1 = (const float*)d_in[1];
    const float* Whh1 = (const float*)d_in[2];
    const float* bih1 = (const float*)d_in[3];
    const float* bhh1 = (const float*)d_in[4];
    const float* Wih2 = (const float*)d_in[5];
    const float* Whh2 = (const float*)d_in[6];
    const float* bih2 = (const float*)d_in[7];
    const float* bhh2 = (const float*)d_in[8];
    const float* Wlin = (const float*)d_in[9];
    const float* blin = (const float*)d_in[10];
    float* ws  = (float*)d_ws;
    float* out = (float*)d_out;

    hipLaunchKernelGGL(prep_kernel, dim3(64), dim3(256), 0, stream,
                       Wih1, Whh1, bih1, bhh1, Wih2, Whh2, bih2, bhh2, Wlin, blin, ws);
    hipLaunchKernelGGL(lstm_kernel, dim3(NBLK), dim3(512), 0, stream, x, ws, out);
}